// Round 14
// baseline (1581.818 us; speedup 1.0000x reference)
//
#include <hip/hip_runtime.h>
#include <stdint.h>

#define DEV __device__ __forceinline__

constexpr int NN = 200000;
constexpr int GSEG = 512;

typedef __attribute__((ext_vector_type(8)))  short   s8v;   // 8 bf16/fp16 bits
typedef __attribute__((ext_vector_type(4)))  float   f4v;
typedef __attribute__((ext_vector_type(16))) float   f16v;
typedef __attribute__((ext_vector_type(4)))  unsigned short u4v;
typedef __attribute__((ext_vector_type(4)))  _Float16 h4v;

DEV void mfma32(const s8v& a, const s8v& b, f16v& c){
  asm volatile("v_mfma_f32_32x32x16_bf16 %0, %1, %2, %0" : "+v"(c) : "v"(a), "v"(b));
}

DEV unsigned short f2bs(float f){
  union { float f; uint32_t u; } v; v.f = f;
  uint32_t u = v.u;
  u = u + 0x7fffu + ((u >> 16) & 1u);          // RNE
  return (unsigned short)(u >> 16);
}
DEV float b2f(unsigned short s){
  union { uint32_t u; float f; } v; v.u = ((uint32_t)s) << 16;
  return v.f;
}
DEV unsigned short f2h(float f){
  union{ _Float16 h; unsigned short u; } v; v.h = (_Float16)f; return v.u;
}
DEV s8v cvt8(f4v a, f4v b){
  s8v r;
  r[0]=(short)f2bs(a[0]); r[1]=(short)f2bs(a[1]); r[2]=(short)f2bs(a[2]); r[3]=(short)f2bs(a[3]);
  r[4]=(short)f2bs(b[0]); r[5]=(short)f2bs(b[1]); r[6]=(short)f2bs(b[2]); r[7]=(short)f2bs(b[3]);
  return r;
}

DEV void gload_lds16(const void* g, void* l){
  __builtin_amdgcn_global_load_lds(
      (const __attribute__((address_space(1))) void*)g,
      (__attribute__((address_space(3))) void*)l, 16, 0, 0);
}

DEV u4v shfl_xor32_u4(u4v v){
  union { u4v q; long long l; } a, b;
  a.q = v;
  b.l = __shfl_xor(a.l, 32);
  return b.q;
}

// ---------------------------------------------------------------------------
// FL (fragment-linear) state layout (R12-verified):
//   16B unit (node n, col-octet o) at short-offset (n>>5)*8192 + o*256 + (n&31)*8.
//   K-loop reader (lane l32,h at slice k16): o = k16*2+h -> wave reads 1KB contiguous.
// ---------------------------------------------------------------------------

// B-fragment loader (R12 verbatim).
// BSRC: 0 = bf16 X(FL); 1 = f32 X; 2 = concat(bf16 X(FL), f32 gsum); 3 = concat(f32 X, f32 gsum)
template<int BSRC>
DEV s8v load_bfrag(const unsigned short* Xb, const float* Xf, const float* gsum,
                   int row, int g, int k16, int h){
  if constexpr(BSRC==0){
    return *(const s8v*)(Xb + (size_t)(row>>5)*8192 + (size_t)(k16*2+h)*256 + (row&31)*8);
  } else if constexpr(BSRC==1){
    const float* p = Xf + (size_t)row*256 + k16*16 + h*8;
    return cvt8(*(const f4v*)p, *(const f4v*)(p+4));
  } else if constexpr(BSRC==2){
    if(k16 < 16)
      return *(const s8v*)(Xb + (size_t)(row>>5)*8192 + (size_t)(k16*2+h)*256 + (row&31)*8);
    const float* p = gsum + (size_t)g*256 + (k16-16)*16 + h*8;
    return cvt8(*(const f4v*)p, *(const f4v*)(p+4));
  } else {
    if(k16 < 16){
      const float* p = Xf + (size_t)row*256 + k16*16 + h*8;
      return cvt8(*(const f4v*)p, *(const f4v*)(p+4));
    }
    const float* p = gsum + (size_t)g*256 + (k16-16)*16 + h*8;
    return cvt8(*(const f4v*)p, *(const f4v*)(p+4));
  }
}

// ---------------------------------------------------------------------------
// gemm_ln2 — 512-thread / 256-row block version of R12's gemm_ln (MODE0/1).
// Each of the 8 waves (p=wid>>2, wr=(wid>>1)&1, wc=wid&1) runs the BYTE-
// IDENTICAL R12 per-wave program: acc[2][NI] = 64 VGPRs, same k2 loop, same
// FL loads, same verified epilogue body. Only block geometry changes:
// grid halves (rounds 3.05->1.5) and 16 waves/CU fit at ~108 VGPRs.
// __launch_bounds__(512,1): register cap stays 512 (the R5/R7 cap-class bug
// cannot trigger).
// ---------------------------------------------------------------------------
template<int DOUT,int KDIM,int BSRC,int MODE,int RES,int WRH>
__global__ __launch_bounds__(512,1) void gemm_ln2(
    const unsigned short* Xb, const float* Xf, const float* gsumIn, const int* batch,
    const unsigned short* PW, const float* bias, const float* lng, const float* lnb,
    const float* xresf, const unsigned short* xresh, const unsigned short* xresb,
    unsigned short* outb, unsigned short* outh)
{
  constexpr int NM  = DOUT/32;       // frags per k16 slice
  constexpr int NI  = DOUT/64;       // i-frags per wave
  constexpr int CHB = NM*4096;       // chunk bytes (4 k16 slices)
  constexpr int ITER= CHB/8192;      // 16B stage ops per thread (512 threads)
  __shared__ __align__(16) char smem[CHB + 4096];

  const int tid  = threadIdx.x;
  const int lane = tid & 63;
  const int wid  = tid >> 6;                 // 0..7
  const int p  = wid >> 2;                   // row-pair half
  const int wr = (wid >> 1) & 1;             // 64-row group
  const int wc = wid & 1;                    // col half
  const int l32 = lane & 31, h = lane >> 5;
  const int rb   = (int)blockIdx.x * 256;
  const int row0 = rb + p*128 + wr*64 + l32;
  const int row1 = row0 + 32;
  const int r0c = row0 < NN ? row0 : NN-1;
  const int r1c = row1 < NN ? row1 : NN-1;

  f16v acc[2][NI];
  #pragma unroll
  for(int ni=0; ni<NI; ++ni){
    #pragma unroll
    for(int rq=0; rq<4; ++rq){
      f4v bv = *(const f4v*)(bias + wc*(DOUT/2) + ni*32 + 8*rq + 4*h);
      #pragma unroll
      for(int j=0;j<4;++j){ acc[0][ni][rq*4+j]=bv[j]; acc[1][ni][rq*4+j]=bv[j]; }
    }
  }

  int g0=0, g1=0;
  if constexpr(BSRC>=2){ g0 = batch[r0c]; g1 = batch[r1c]; }

  for(int kc=0; kc<KDIM/64; ++kc){
    const unsigned short* src = PW + (size_t)kc*(CHB/2);
    #pragma unroll
    for(int it=0; it<ITER; ++it){
      int idx = it*512 + tid;
      gload_lds16(src + (size_t)idx*8, smem + (it*512 + wid*64 + lane)*16);
    }
    __syncthreads();
    #pragma unroll
    for(int k2=0;k2<4;++k2){
      const int k16 = kc*4 + k2;
      s8v b0 = load_bfrag<BSRC>(Xb, Xf, gsumIn, r0c, g0, k16, h);
      s8v b1 = load_bfrag<BSRC>(Xb, Xf, gsumIn, r1c, g1, k16, h);
      #pragma unroll
      for(int ni=0; ni<NI; ++ni){
        s8v a = *(const s8v*)(smem + ((k2*NM + wc*NI + ni)*64 + lane)*16);
        mfma32(a, b0, acc[0][ni]);
        mfma32(a, b1, acc[1][ni]);
      }
    }
    __syncthreads();
  }

  // residual add (MODE1) or relu (MODE0) — R12 per-wave body verbatim
  #pragma unroll
  for(int nj=0;nj<2;++nj){
    if constexpr(MODE==1){
      const int rr = nj ? r1c : r0c;
      #pragma unroll
      for(int ni=0;ni<NI;++ni){
        #pragma unroll
        for(int rq=0;rq<4;++rq){
          const int c4 = wc*(DOUT/2) + ni*32 + 8*rq + 4*h;
          f4v rv;
          if constexpr(RES==1){
            rv = *(const f4v*)(xresf + (size_t)rr*256 + c4);
          } else if constexpr(RES==2){
            const int o = wc*16 + ni*4 + rq;
            h4v hv = *(const h4v*)(xresh + (size_t)(rr>>5)*8192 + (size_t)o*256 + (rr&31)*8 + 4*h);
            #pragma unroll
            for(int j=0;j<4;++j) rv[j] = (float)hv[j];
          } else {
            const int o = wc*16 + ni*4 + rq;
            u4v u = *(const u4v*)(xresb + (size_t)(rr>>5)*8192 + (size_t)o*256 + (rr&31)*8 + 4*h);
            #pragma unroll
            for(int j=0;j<4;++j) rv[j] = b2f(u[j]);
          }
          #pragma unroll
          for(int j=0;j<4;++j) acc[nj][ni][rq*4+j] += rv[j];
        }
      }
    } else {
      #pragma unroll
      for(int ni=0;ni<NI;++ni)
        #pragma unroll
        for(int r=0;r<16;++r) acc[nj][ni][r] = fmaxf(acc[nj][ni][r], 0.f);
    }
  }
  // row stats: slot = (p*2+wr)*2+nj  (8 slots x 32 x 2 float2 = 4KB)
  float s[2]={0.f,0.f}, q[2]={0.f,0.f};
  #pragma unroll
  for(int nj=0;nj<2;++nj)
    #pragma unroll
    for(int ni=0;ni<NI;++ni)
      #pragma unroll
      for(int r=0;r<16;++r){ float v = acc[nj][ni][r]; s[nj]+=v; q[nj]=fmaf(v,v,q[nj]); }
  #pragma unroll
  for(int nj=0;nj<2;++nj){ s[nj] += __shfl_xor(s[nj],32); q[nj] += __shfl_xor(q[nj],32); }
  float2* st = (float2*)(smem + CHB);
  if(lane < 32){
    st[((((p*2+wr)*2+0)*32)+lane)*2 + wc] = make_float2(s[0], q[0]);
    st[((((p*2+wr)*2+1)*32)+lane)*2 + wc] = make_float2(s[1], q[1]);
  }
  __syncthreads();
  float mu[2], rs[2];
  #pragma unroll
  for(int nj=0;nj<2;++nj){
    f4v v = *(const f4v*)(st + ((((p*2+wr)*2+nj)*32)+l32)*2);
    float S = v[0]+v[2], Q = v[1]+v[3];
    mu[nj] = S*(1.f/256.f);
    float var = Q*(1.f/256.f) - mu[nj]*mu[nj];
    rs[nj] = rsqrtf(var + 1e-5f);
  }
  // ---- FL state store (R12-verified body) ----
  #pragma unroll
  for(int nj=0;nj<2;++nj){
    const int rowS = nj ? row1 : row0;
    #pragma unroll
    for(int t=0;t<8;++t){
      const int niE = (16*t)>>5,     rqE = (2*t)&3;
      const int niO = (16*t+8)>>5,   rqO = (2*t+1)&3;
      f4v fe, fo;
      {
        const int c4 = wc*(DOUT/2) + niE*32 + 8*rqE + 4*h;
        f4v gv = *(const f4v*)(lng + c4);
        f4v bv = *(const f4v*)(lnb + c4);
        #pragma unroll
        for(int j=0;j<4;++j)
          fe[j] = fmaf((acc[nj][niE][rqE*4+j]-mu[nj])*rs[nj], gv[j], bv[j]);
      }
      {
        const int c4 = wc*(DOUT/2) + niO*32 + 8*rqO + 4*h;
        f4v gv = *(const f4v*)(lng + c4);
        f4v bv = *(const f4v*)(lnb + c4);
        #pragma unroll
        for(int j=0;j<4;++j)
          fo[j] = fmaf((acc[nj][niO][rqO*4+j]-mu[nj])*rs[nj], gv[j], bv[j]);
      }
      const int o = wc*16 + 2*t + h;
      {
        u4v qe, qo;
        #pragma unroll
        for(int j=0;j<4;++j){ qe[j] = f2bs(fe[j]); qo[j] = f2bs(fo[j]); }
        u4v snd = h ? qe : qo;
        u4v rcv = shfl_xor32_u4(snd);
        u4v lo4 = h ? rcv : qe;
        u4v hi4 = h ? qo  : rcv;
        if(rowS < NN){
          s8v ov;
          #pragma unroll
          for(int j=0;j<4;++j){ ov[j] = (short)lo4[j]; ov[4+j] = (short)hi4[j]; }
          *(s8v*)(outb + (size_t)(rowS>>5)*8192 + (size_t)o*256 + (rowS&31)*8) = ov;
        }
      }
      if constexpr(WRH){
        u4v qe, qo;
        #pragma unroll
        for(int j=0;j<4;++j){ qe[j] = f2h(fe[j]); qo[j] = f2h(fo[j]); }
        u4v snd = h ? qe : qo;
        u4v rcv = shfl_xor32_u4(snd);
        u4v lo4 = h ? rcv : qe;
        u4v hi4 = h ? qo  : rcv;
        if(rowS < NN){
          s8v ov;
          #pragma unroll
          for(int j=0;j<4;++j){ ov[j] = (short)lo4[j]; ov[4+j] = (short)hi4[j]; }
          *(s8v*)(outh + (size_t)(rowS>>5)*8192 + (size_t)o*256 + (rowS&31)*8) = ov;
        }
      }
    }
  }
}

// ---------------------------------------------------------------------------
// Head kernel (R12's gemm_ln, MODE2 path only): 256 threads, 128 rows,
// f32 row-major chunked transpose store via sT. VERBATIM.
// ---------------------------------------------------------------------------
__global__ __launch_bounds__(256,2) void head_k(
    const unsigned short* Xb, const unsigned short* PW, const float* hb, float* outf)
{
  constexpr int DOUT = 128;
  constexpr int NM  = DOUT/32;
  constexpr int NI  = DOUT/64;
  constexpr int CHB = NM*4096;
  constexpr int ITER= CHB/4096;
  __shared__ __align__(16) char smem[CHB + 4096];
  __shared__ __align__(16) char sT[32768];

  const int tid  = threadIdx.x;
  const int lane = tid & 63;
  const int wid  = tid >> 6;
  const int wr = wid >> 1, wc = wid & 1;
  const int l32 = lane & 31, h = lane >> 5;
  const int rb   = (int)blockIdx.x * 128;
  const int row0 = rb + wr*64 + l32;
  const int row1 = row0 + 32;
  const int r0c = row0 < NN ? row0 : NN-1;
  const int r1c = row1 < NN ? row1 : NN-1;

  f16v acc[2][NI];
  #pragma unroll
  for(int ni=0; ni<NI; ++ni){
    #pragma unroll
    for(int rq=0; rq<4; ++rq){
      f4v bv = *(const f4v*)(hb + wc*(DOUT/2) + ni*32 + 8*rq + 4*h);
      #pragma unroll
      for(int j=0;j<4;++j){ acc[0][ni][rq*4+j]=bv[j]; acc[1][ni][rq*4+j]=bv[j]; }
    }
  }

  for(int kc=0; kc<4; ++kc){
    const unsigned short* src = PW + (size_t)kc*(CHB/2);
    #pragma unroll
    for(int it=0; it<ITER; ++it){
      int idx = it*256 + tid;
      gload_lds16(src + (size_t)idx*8, smem + (it*256 + wid*64)*16);
    }
    __syncthreads();
    #pragma unroll
    for(int k2=0;k2<4;++k2){
      const int k16 = kc*4 + k2;
      s8v b0 = *(const s8v*)(Xb + (size_t)(r0c>>5)*8192 + (size_t)(k16*2+h)*256 + (r0c&31)*8);
      s8v b1 = *(const s8v*)(Xb + (size_t)(r1c>>5)*8192 + (size_t)(k16*2+h)*256 + (r1c&31)*8);
      #pragma unroll
      for(int ni=0; ni<NI; ++ni){
        s8v a = *(const s8v*)(smem + ((k2*NM + wc*NI + ni)*64 + lane)*16);
        mfma32(a, b0, acc[0][ni]);
        mfma32(a, b1, acc[1][ni]);
      }
    }
    __syncthreads();
  }

  for(int chunk=0; chunk<2; ++chunk){
    if(chunk) __syncthreads();
    if(wr == chunk){
      #pragma unroll
      for(int nj=0;nj<2;++nj){
        #pragma unroll
        for(int ni=0;ni<NI;++ni){
          #pragma unroll
          for(int rq=0;rq<4;++rq){
            const int c4 = wc*(DOUT/2) + ni*32 + 8*rq + 4*h;
            f4v o;
            #pragma unroll
            for(int j=0;j<4;++j) o[j] = acc[nj][ni][rq*4+j];
            *(f4v*)(sT + (nj*32+l32)*512 + ((c4*4) ^ (l32<<4))) = o;
          }
        }
      }
    }
    __syncthreads();
    #pragma unroll
    for(int i=0;i<8;++i){
      const int r = i*8 + (tid>>5);
      const int c = tid & 31;
      const int grow = rb + chunk*64 + r;
      if(grow < NN)
        *(f4v*)(outf + (size_t)grow*DOUT + c*4) =
            *(const f4v*)(sT + r*512 + ((c*16) ^ ((r&31)<<4)));
    }
  }
}

// ---------------------------------------------------------------------------
// K2: phi_x = h1 @ W2 + b2 -> segment-sum into gsum (R12 VERBATIM).
// ---------------------------------------------------------------------------
__global__ __launch_bounds__(256,2) void gemm_segsum(
    const unsigned short* Xb, const unsigned short* PW, const float* bias,
    const int* batch, float* gsum)
{
  __shared__ __align__(16) char smem[32768];
  const int tid = threadIdx.x, lane = tid&63, wid = tid>>6;
  const int wr = wid>>1, wc = wid&1, l32 = lane&31, h = lane>>5;
  const int rb = (int)blockIdx.x*128;
  const int ra0 = rb + wr*64 + l32;
  const int ra1 = ra0 + 32;
  const int r0c = ra0 < NN ? ra0 : NN-1;
  const int r1c = ra1 < NN ? ra1 : NN-1;
  const int browi = rb + wr*64 + lane;
  const int b_l = (browi < NN) ? batch[browi] : 0x7fffffff;

  f16v acc[2][4];
  #pragma unroll
  for(int n=0;n<4;++n){
    float bv = bias[wc*128 + n*32 + l32];
    #pragma unroll
    for(int m=0;m<2;++m)
      #pragma unroll
      for(int r=0;r<16;++r) acc[m][n][r] = bv;
  }

  for(int kc=0; kc<4; ++kc){
    const unsigned short* src = PW + (size_t)kc*16384;
    #pragma unroll
    for(int it=0; it<8; ++it){
      int idx = it*256 + tid;
      gload_lds16(src + (size_t)idx*8, smem + (it*256 + wid*64)*16);
    }
    __syncthreads();
    #pragma unroll
    for(int k2=0;k2<4;++k2){
      const int k16 = kc*4+k2;
      s8v a0 = *(const s8v*)(Xb + (size_t)(r0c>>5)*8192 + (size_t)(k16*2+h)*256 + (r0c&31)*8);
      s8v a1 = *(const s8v*)(Xb + (size_t)(r1c>>5)*8192 + (size_t)(k16*2+h)*256 + (r1c&31)*8);
      #pragma unroll
      for(int n=0;n<4;++n){
        s8v bw = *(const s8v*)(smem + ((k2*8 + wc*4 + n)*64 + lane)*16);
        mfma32(a0, bw, acc[0][n]);
        mfma32(a1, bw, acc[1][n]);
      }
    }
    __syncthreads();
  }

  int lo = 0;
  while(lo < 64){
    int g = __shfl(b_l, lo);
    unsigned long long mb = __ballot(b_l == g);
    int hi = lo + __popcll(mb);
    if(g < GSEG){
      #pragma unroll
      for(int n=0;n<4;++n){
        float sum = 0.f;
        #pragma unroll
        for(int m=0;m<2;++m){
          if(hi <= m*32 || lo >= m*32+32) continue;
          #pragma unroll
          for(int r=0;r<16;++r){
            int lr = m*32 + (r&3) + 8*(r>>2) + 4*h;
            sum += (lr >= lo && lr < hi) ? acc[m][n][r] : 0.f;
          }
        }
        sum += __shfl_xor(sum, 32);
        if(lane < 32) atomicAdd(&gsum[(size_t)g*256 + wc*128 + n*32 + lane], sum);
      }
    }
    lo = hi;
  }
}

// ---------------------------------------------------------------------------
// Weight pack (round-1 VERBATIM): fp32 [K][Dout] -> bf16 fragment-linear
// ---------------------------------------------------------------------------
__global__ void pack_weights(const float* phi_w1, const float* phi_w2,
                             const float* psi_w1, const float* psi_w2,
                             const float* head_w, unsigned short* pw)
{
  int o = (int)blockIdx.x*256 + (int)threadIdx.x;
  if(o >= 167936) return;
  const float* src; unsigned short* dst; int Dout, oo;
  if(o < 32768){        int l=o>>13;            oo=o&8191;  src=phi_w1+(size_t)l*65536;  dst=pw+(size_t)l*65536;           Dout=256; }
  else if(o < 65536){   int t=o-32768,l=t>>13;  oo=t&8191;  src=phi_w2+(size_t)l*65536;  dst=pw+262144+(size_t)l*65536;    Dout=256; }
  else if(o < 131072){  int t=o-65536,l=t>>14;  oo=t&16383; src=psi_w1+(size_t)l*131072; dst=pw+524288+(size_t)l*131072;   Dout=256; }
  else if(o < 163840){  int t=o-131072,l=t>>13; oo=t&8191;  src=psi_w2+(size_t)l*65536;  dst=pw+1048576+(size_t)l*65536;   Dout=256; }
  else{                 oo=o-163840;            src=head_w; dst=pw+1310720;                                                Dout=128; }
  const int NM = Dout/32;
  int lane = oo & 63;
  int m   = (oo>>6) % NM;
  int k16 = (oo>>6) / NM;
  int kb  = k16*16 + (lane>>5)*8;
  int col = m*32 + (lane&31);
  #pragma unroll
  for(int jj=0;jj<8;++jj) dst[(size_t)oo*8 + jj] = f2bs(src[(size_t)(kb+jj)*Dout + col]);
}

// ---------------------------------------------------------------------------
extern "C" void kernel_launch(void* const* d_in, const int* in_sizes, int n_in,
                              void* d_out, int out_size, void* d_ws, size_t ws_size,
                              hipStream_t stream)
{
  (void)in_sizes; (void)n_in; (void)out_size;
  const float* x0       = (const float*)d_in[0];
  const int*   batch    = (const int*)  d_in[1];
  const float* phi_w1   = (const float*)d_in[2];
  const float* phi_b1   = (const float*)d_in[3];
  const float* phi_ln_g = (const float*)d_in[4];
  const float* phi_ln_b = (const float*)d_in[5];
  const float* phi_w2   = (const float*)d_in[6];
  const float* phi_b2   = (const float*)d_in[7];
  const float* psi_w1   = (const float*)d_in[8];
  const float* psi_b1   = (const float*)d_in[9];
  const float* psi_ln_g = (const float*)d_in[10];
  const float* psi_ln_b = (const float*)d_in[11];
  const float* psi_w2   = (const float*)d_in[12];
  const float* psi_b2   = (const float*)d_in[13];
  const float* out_ln_g = (const float*)d_in[14];
  const float* out_ln_b = (const float*)d_in[15];
  const float* head_w   = (const float*)d_in[16];
  const float* head_b   = (const float*)d_in[17];

  char* ws = (char*)d_ws;
  unsigned short* pw = (unsigned short*)ws;               // packed bf16 weights (2.7MB)
  float* gsum        = (float*)(ws + 4194304);            // 524,288 B
  unsigned short* hb = (unsigned short*)(ws + 8388608);   // 102,400,000 B h1/h2 (FL)
  const bool dual = (ws_size >= 315588608ull);
  unsigned short* xb = dual ? (unsigned short*)(ws + 110788608)
                            : (unsigned short*)d_out;     // bf16 state (FL)
  unsigned short* xh = dual ? (unsigned short*)(ws + 213188608) : nullptr; // fp16 state (FL)

  const int gridL = (NN + 255)/256;   // 782  (gemm_ln2: 256-row, 512-thread)
  const int gridS = (NN + 127)/128;   // 1563 (segsum, head: 128-row, 256-thread)

  pack_weights<<<656,256,0,stream>>>(phi_w1, phi_w2, psi_w1, psi_w2, head_w, pw);

  for(int l=0;l<4;++l){
    const unsigned short* pw_phi1 = pw + (size_t)l*65536;
    const unsigned short* pw_phi2 = pw + 262144 + (size_t)l*65536;
    const unsigned short* pw_psi1 = pw + 524288 + (size_t)l*131072;
    const unsigned short* pw_psi2 = pw + 1048576 + (size_t)l*65536;
    const float* b1 = phi_b1 + l*256, *g1 = phi_ln_g + l*256, *n1 = phi_ln_b + l*256;
    const float* b2 = phi_b2 + l*256;
    const float* p1 = psi_b1 + l*256, *pg = psi_ln_g + l*256, *pn = psi_ln_b + l*256;
    const float* p2 = psi_b2 + l*256;
    const float* og = out_ln_g + l*256, *on = out_ln_b + l*256;

    // K1: h1 = LN(relu(x @ phi_w1 + b1))
    if(l==0)
      gemm_ln2<256,256,1,0,0,0><<<gridL,512,0,stream>>>(nullptr, x0, nullptr, nullptr,
          pw_phi1, b1, g1, n1, nullptr, nullptr, nullptr, hb, nullptr);
    else
      gemm_ln2<256,256,0,0,0,0><<<gridL,512,0,stream>>>(xb, nullptr, nullptr, nullptr,
          pw_phi1, b1, g1, n1, nullptr, nullptr, nullptr, hb, nullptr);

    // K2: gsum = segment_sum(h1 @ phi_w2 + b2)
    hipMemsetAsync(gsum, 0, 524288, stream);
    gemm_segsum<<<gridS,256,0,stream>>>(hb, pw_phi2, b2, batch, gsum);

    // K3: h2 = LN(relu([x | gsum[batch]] @ psi_w1 + b1'))
    if(l==0)
      gemm_ln2<256,512,3,0,0,0><<<gridL,512,0,stream>>>(nullptr, x0, gsum, batch,
          pw_psi1, p1, pg, pn, nullptr, nullptr, nullptr, hb, nullptr);
    else
      gemm_ln2<256,512,2,0,0,0><<<gridL,512,0,stream>>>(xb, nullptr, gsum, batch,
          pw_psi1, p1, pg, pn, nullptr, nullptr, nullptr, hb, nullptr);

    // K4: x = out_LN(x + h2 @ psi_w2 + b2')
    if(l==0){
      if(dual)
        gemm_ln2<256,256,0,1,1,1><<<gridL,512,0,stream>>>(hb, nullptr, nullptr, nullptr,
            pw_psi2, p2, og, on, x0, nullptr, nullptr, xb, xh);
      else
        gemm_ln2<256,256,0,1,1,0><<<gridL,512,0,stream>>>(hb, nullptr, nullptr, nullptr,
            pw_psi2, p2, og, on, x0, nullptr, nullptr, xb, nullptr);
    } else if(l<3){
      if(dual)
        gemm_ln2<256,256,0,1,2,1><<<gridL,512,0,stream>>>(hb, nullptr, nullptr, nullptr,
            pw_psi2, p2, og, on, nullptr, xh, nullptr, xb, xh);
      else
        gemm_ln2<256,256,0,1,3,0><<<gridL,512,0,stream>>>(hb, nullptr, nullptr, nullptr,
            pw_psi2, p2, og, on, nullptr, nullptr, xb, xb, nullptr);
    } else {
      if(dual)
        gemm_ln2<256,256,0,1,2,0><<<gridL,512,0,stream>>>(hb, nullptr, nullptr, nullptr,
            pw_psi2, p2, og, on, nullptr, xh, nullptr, xb, nullptr);
      else
        gemm_ln2<256,256,0,1,3,0><<<gridL,512,0,stream>>>(hb, nullptr, nullptr, nullptr,
            pw_psi2, p2, og, on, nullptr, nullptr, xb, xb, nullptr);
    }
  }

  // head: out = x @ head_w + head_b (reads FL xb)
  head_k<<<gridS,256,0,stream>>>(xb, pw + 1310720, head_b, (float*)d_out);
}

// Round 15
// 1513.328 us; speedup vs baseline: 1.0453x; 1.0453x over previous
//
#include <hip/hip_runtime.h>
#include <stdint.h>

#define DEV __device__ __forceinline__

constexpr int NN = 200000;
constexpr int GSEG = 512;

typedef __attribute__((ext_vector_type(8)))  short   s8v;   // 8 bf16/fp16 bits
typedef __attribute__((ext_vector_type(4)))  float   f4v;
typedef __attribute__((ext_vector_type(16))) float   f16v;
typedef __attribute__((ext_vector_type(4)))  unsigned short u4v;
typedef __attribute__((ext_vector_type(4)))  _Float16 h4v;

DEV void mfma32(const s8v& a, const s8v& b, f16v& c){
  asm volatile("v_mfma_f32_32x32x16_bf16 %0, %1, %2, %0" : "+v"(c) : "v"(a), "v"(b));
}

DEV unsigned short f2bs(float f){
  union { float f; uint32_t u; } v; v.f = f;
  uint32_t u = v.u;
  u = u + 0x7fffu + ((u >> 16) & 1u);          // RNE
  return (unsigned short)(u >> 16);
}
DEV float b2f(unsigned short s){
  union { uint32_t u; float f; } v; v.u = ((uint32_t)s) << 16;
  return v.f;
}
DEV unsigned short f2h(float f){
  union{ _Float16 h; unsigned short u; } v; v.h = (_Float16)f; return v.u;
}
DEV s8v cvt8(f4v a, f4v b){
  s8v r;
  r[0]=(short)f2bs(a[0]); r[1]=(short)f2bs(a[1]); r[2]=(short)f2bs(a[2]); r[3]=(short)f2bs(a[3]);
  r[4]=(short)f2bs(b[0]); r[5]=(short)f2bs(b[1]); r[6]=(short)f2bs(b[2]); r[7]=(short)f2bs(b[3]);
  return r;
}

DEV void gload_lds16(const void* g, void* l){
  __builtin_amdgcn_global_load_lds(
      (const __attribute__((address_space(1))) void*)g,
      (__attribute__((address_space(3))) void*)l, 16, 0, 0);
}

DEV u4v shfl_xor32_u4(u4v v){
  union { u4v q; long long l; } a, b;
  a.q = v;
  b.l = __shfl_xor(a.l, 32);
  return b.q;
}

// ---------------------------------------------------------------------------
// FL (fragment-linear) state layout (R12-verified):
//   16B unit (node n, col-octet o) at short-offset (n>>5)*8192 + o*256 + (n&31)*8.
//   K-loop reader (lane l32,h at slice k16): o = k16*2+h -> wave reads 1KB contiguous.
// ---------------------------------------------------------------------------

// B-fragment loader (R12 verbatim).
// BSRC: 0 = bf16 X(FL); 1 = f32 X; 2 = concat(bf16 X(FL), f32 gsum); 3 = concat(f32 X, f32 gsum)
template<int BSRC>
DEV s8v load_bfrag(const unsigned short* Xb, const float* Xf, const float* gsum,
                   int row, int g, int k16, int h){
  if constexpr(BSRC==0){
    return *(const s8v*)(Xb + (size_t)(row>>5)*8192 + (size_t)(k16*2+h)*256 + (row&31)*8);
  } else if constexpr(BSRC==1){
    const float* p = Xf + (size_t)row*256 + k16*16 + h*8;
    return cvt8(*(const f4v*)p, *(const f4v*)(p+4));
  } else if constexpr(BSRC==2){
    if(k16 < 16)
      return *(const s8v*)(Xb + (size_t)(row>>5)*8192 + (size_t)(k16*2+h)*256 + (row&31)*8);
    const float* p = gsum + (size_t)g*256 + (k16-16)*16 + h*8;
    return cvt8(*(const f4v*)p, *(const f4v*)(p+4));
  } else {
    if(k16 < 16){
      const float* p = Xf + (size_t)row*256 + k16*16 + h*8;
      return cvt8(*(const f4v*)p, *(const f4v*)(p+4));
    }
    const float* p = gsum + (size_t)g*256 + (k16-16)*16 + h*8;
    return cvt8(*(const f4v*)p, *(const f4v*)(p+4));
  }
}

// ---------------------------------------------------------------------------
// Main fused GEMM — R12 source verbatim with CHB doubled again: 8 k16-slices
// (64KB weights) per stage->barrier->consume->barrier window. K=256 kernels
// run 2 windows/block (was 4), K=512 runs 4 (was 8); 16 FL b-loads in flight
// per window. LDS 66KB -> still 2 blocks/CU at bounds (256,2). Ordering
// per chunk identical to the R11/R12 pattern (the 100%-pass class).
// MODE: 0 = LN(relu(.)) -> bf16 FL out
//       1 = (.)+residual, out_LN -> bf16 FL out (+ fp16 FL out if WRH)
//       2 = plain f32 row-major store via sT (head, d_out)
// RES:  1 = f32 row-major residual (L0), 2 = fp16 FL, 3 = bf16 FL
// ---------------------------------------------------------------------------
template<int DOUT,int KDIM,int BSRC,int MODE,int RES,int WRH>
__global__ __launch_bounds__(256,2) void gemm_ln(
    const unsigned short* Xb, const float* Xf, const float* gsumIn, const int* batch,
    const unsigned short* PW, const float* bias, const float* lng, const float* lnb,
    const float* xresf, const unsigned short* xresh, const unsigned short* xresb,
    unsigned short* outb, unsigned short* outh, float* outf)
{
  constexpr int NM  = DOUT/32;       // frags per k16 slice
  constexpr int NI  = DOUT/64;       // i-frags per wave
  constexpr int CHB = NM*8192;       // chunk bytes (8 k16 slices — doubled again)
  constexpr int ITER= CHB/4096;
  __shared__ __align__(16) char smem[CHB + 2048];
  __shared__ __align__(16) char sT[(MODE==2) ? 32768 : 16];  // head only

  const int tid  = threadIdx.x;
  const int lane = tid & 63;
  const int wid  = tid >> 6;
  const int wr = wid >> 1, wc = wid & 1;
  const int l32 = lane & 31, h = lane >> 5;
  const int rb   = (int)blockIdx.x * 128;
  const int row0 = rb + wr*64 + l32;
  const int row1 = row0 + 32;
  const int r0c = row0 < NN ? row0 : NN-1;
  const int r1c = row1 < NN ? row1 : NN-1;

  f16v acc[2][NI];
  #pragma unroll
  for(int ni=0; ni<NI; ++ni){
    #pragma unroll
    for(int rq=0; rq<4; ++rq){
      f4v bv = *(const f4v*)(bias + wc*(DOUT/2) + ni*32 + 8*rq + 4*h);
      #pragma unroll
      for(int j=0;j<4;++j){ acc[0][ni][rq*4+j]=bv[j]; acc[1][ni][rq*4+j]=bv[j]; }
    }
  }

  int g0=0, g1=0;
  if constexpr(BSRC>=2){ g0 = batch[r0c]; g1 = batch[r1c]; }

  for(int kc=0; kc<KDIM/128; ++kc){
    const unsigned short* src = PW + (size_t)kc*(CHB/2);
    #pragma unroll
    for(int it=0; it<ITER; ++it){
      int idx = it*256 + tid;
      gload_lds16(src + (size_t)idx*8, smem + (it*256 + wid*64)*16);
    }
    __syncthreads();
    #pragma unroll
    for(int k2=0;k2<8;++k2){
      const int k16 = kc*8 + k2;
      s8v b0 = load_bfrag<BSRC>(Xb, Xf, gsumIn, r0c, g0, k16, h);
      s8v b1 = load_bfrag<BSRC>(Xb, Xf, gsumIn, r1c, g1, k16, h);
      #pragma unroll
      for(int ni=0; ni<NI; ++ni){
        s8v a = *(const s8v*)(smem + ((k2*NM + wc*NI + ni)*64 + lane)*16);
        mfma32(a, b0, acc[0][ni]);
        mfma32(a, b1, acc[1][ni]);
      }
    }
    __syncthreads();
  }

  if constexpr(MODE==0 || MODE==1){
    // residual add (MODE1) or relu (MODE0)
    #pragma unroll
    for(int nj=0;nj<2;++nj){
      if constexpr(MODE==1){
        const int rr = nj ? r1c : r0c;
        #pragma unroll
        for(int ni=0;ni<NI;++ni){
          #pragma unroll
          for(int rq=0;rq<4;++rq){
            const int c4 = wc*(DOUT/2) + ni*32 + 8*rq + 4*h;
            f4v rv;
            if constexpr(RES==1){
              rv = *(const f4v*)(xresf + (size_t)rr*256 + c4);
            } else if constexpr(RES==2){
              const int o = wc*16 + ni*4 + rq;
              h4v hv = *(const h4v*)(xresh + (size_t)(rr>>5)*8192 + (size_t)o*256 + (rr&31)*8 + 4*h);
              #pragma unroll
              for(int j=0;j<4;++j) rv[j] = (float)hv[j];
            } else {
              const int o = wc*16 + ni*4 + rq;
              u4v u = *(const u4v*)(xresb + (size_t)(rr>>5)*8192 + (size_t)o*256 + (rr&31)*8 + 4*h);
              #pragma unroll
              for(int j=0;j<4;++j) rv[j] = b2f(u[j]);
            }
            #pragma unroll
            for(int j=0;j<4;++j) acc[nj][ni][rq*4+j] += rv[j];
          }
        }
      } else {
        #pragma unroll
        for(int ni=0;ni<NI;++ni)
          #pragma unroll
          for(int r=0;r<16;++r) acc[nj][ni][r] = fmaxf(acc[nj][ni][r], 0.f);
      }
    }
    // row stats (R12 verbatim)
    float s[2]={0.f,0.f}, q[2]={0.f,0.f};
    #pragma unroll
    for(int nj=0;nj<2;++nj)
      #pragma unroll
      for(int ni=0;ni<NI;++ni)
        #pragma unroll
        for(int r=0;r<16;++r){ float v = acc[nj][ni][r]; s[nj]+=v; q[nj]=fmaf(v,v,q[nj]); }
    #pragma unroll
    for(int nj=0;nj<2;++nj){ s[nj] += __shfl_xor(s[nj],32); q[nj] += __shfl_xor(q[nj],32); }
    float2* st = (float2*)(smem + CHB);
    if(lane < 32){
      st[(((wr*2+0)*32)+lane)*2 + wc] = make_float2(s[0], q[0]);
      st[(((wr*2+1)*32)+lane)*2 + wc] = make_float2(s[1], q[1]);
    }
    __syncthreads();
    float mu[2], rs[2];
    #pragma unroll
    for(int nj=0;nj<2;++nj){
      f4v v = *(const f4v*)(st + (((wr*2+nj)*32)+l32)*2);
      float S = v[0]+v[2], Q = v[1]+v[3];
      mu[nj] = S*(1.f/256.f);
      float var = Q*(1.f/256.f) - mu[nj]*mu[nj];
      rs[nj] = rsqrtf(var + 1e-5f);
    }
    // ---- FL state store (R12-verified body) ----
    #pragma unroll
    for(int nj=0;nj<2;++nj){
      const int rowS = nj ? row1 : row0;
      #pragma unroll
      for(int t=0;t<8;++t){
        const int niE = (16*t)>>5,     rqE = (2*t)&3;
        const int niO = (16*t+8)>>5,   rqO = (2*t+1)&3;
        f4v fe, fo;
        {
          const int c4 = wc*(DOUT/2) + niE*32 + 8*rqE + 4*h;
          f4v gv = *(const f4v*)(lng + c4);
          f4v bv = *(const f4v*)(lnb + c4);
          #pragma unroll
          for(int j=0;j<4;++j)
            fe[j] = fmaf((acc[nj][niE][rqE*4+j]-mu[nj])*rs[nj], gv[j], bv[j]);
        }
        {
          const int c4 = wc*(DOUT/2) + niO*32 + 8*rqO + 4*h;
          f4v gv = *(const f4v*)(lng + c4);
          f4v bv = *(const f4v*)(lnb + c4);
          #pragma unroll
          for(int j=0;j<4;++j)
            fo[j] = fmaf((acc[nj][niO][rqO*4+j]-mu[nj])*rs[nj], gv[j], bv[j]);
        }
        const int o = wc*16 + 2*t + h;
        {
          u4v qe, qo;
          #pragma unroll
          for(int j=0;j<4;++j){ qe[j] = f2bs(fe[j]); qo[j] = f2bs(fo[j]); }
          u4v snd = h ? qe : qo;
          u4v rcv = shfl_xor32_u4(snd);
          u4v lo4 = h ? rcv : qe;
          u4v hi4 = h ? qo  : rcv;
          if(rowS < NN){
            s8v ov;
            #pragma unroll
            for(int j=0;j<4;++j){ ov[j] = (short)lo4[j]; ov[4+j] = (short)hi4[j]; }
            *(s8v*)(outb + (size_t)(rowS>>5)*8192 + (size_t)o*256 + (rowS&31)*8) = ov;
          }
        }
        if constexpr(WRH){
          u4v qe, qo;
          #pragma unroll
          for(int j=0;j<4;++j){ qe[j] = f2h(fe[j]); qo[j] = f2h(fo[j]); }
          u4v snd = h ? qe : qo;
          u4v rcv = shfl_xor32_u4(snd);
          u4v lo4 = h ? rcv : qe;
          u4v hi4 = h ? qo  : rcv;
          if(rowS < NN){
            s8v ov;
            #pragma unroll
            for(int j=0;j<4;++j){ ov[j] = (short)lo4[j]; ov[4+j] = (short)hi4[j]; }
            *(s8v*)(outh + (size_t)(rowS>>5)*8192 + (size_t)o*256 + (rowS&31)*8) = ov;
          }
        }
      }
    }
  } else {
    // MODE2 head: f32 row-major chunked transpose store via sT (R12 verbatim)
    for(int chunk=0; chunk<2; ++chunk){
      if(chunk) __syncthreads();
      if(wr == chunk){
        #pragma unroll
        for(int nj=0;nj<2;++nj){
          #pragma unroll
          for(int ni=0;ni<NI;++ni){
            #pragma unroll
            for(int rq=0;rq<4;++rq){
              const int c4 = wc*(DOUT/2) + ni*32 + 8*rq + 4*h;
              f4v o;
              #pragma unroll
              for(int j=0;j<4;++j) o[j] = acc[nj][ni][rq*4+j];
              *(f4v*)(sT + (nj*32+l32)*512 + ((c4*4) ^ (l32<<4))) = o;
            }
          }
        }
      }
      __syncthreads();
      #pragma unroll
      for(int i=0;i<8;++i){
        const int r = i*8 + (tid>>5);
        const int c = tid & 31;
        const int grow = rb + chunk*64 + r;
        if(grow < NN)
          *(f4v*)(outf + (size_t)grow*DOUT + c*4) =
              *(const f4v*)(sT + r*512 + ((c*16) ^ ((r&31)<<4)));
      }
    }
  }
}

// ---------------------------------------------------------------------------
// K2: phi_x = h1 @ W2 + b2 -> segment-sum into gsum. R12 compute/ballot logic
// verbatim; chunk doubled to 64KB (8 k16 slices) -> 2 windows/block.
// ---------------------------------------------------------------------------
__global__ __launch_bounds__(256,2) void gemm_segsum(
    const unsigned short* Xb, const unsigned short* PW, const float* bias,
    const int* batch, float* gsum)
{
  __shared__ __align__(16) char smem[65536];
  const int tid = threadIdx.x, lane = tid&63, wid = tid>>6;
  const int wr = wid>>1, wc = wid&1, l32 = lane&31, h = lane>>5;
  const int rb = (int)blockIdx.x*128;
  const int ra0 = rb + wr*64 + l32;
  const int ra1 = ra0 + 32;
  const int r0c = ra0 < NN ? ra0 : NN-1;
  const int r1c = ra1 < NN ? ra1 : NN-1;
  const int browi = rb + wr*64 + lane;
  const int b_l = (browi < NN) ? batch[browi] : 0x7fffffff;

  f16v acc[2][4];
  #pragma unroll
  for(int n=0;n<4;++n){
    float bv = bias[wc*128 + n*32 + l32];
    #pragma unroll
    for(int m=0;m<2;++m)
      #pragma unroll
      for(int r=0;r<16;++r) acc[m][n][r] = bv;
  }

  for(int kc=0; kc<2; ++kc){
    const unsigned short* src = PW + (size_t)kc*32768;
    #pragma unroll
    for(int it=0; it<16; ++it){
      int idx = it*256 + tid;
      gload_lds16(src + (size_t)idx*8, smem + (it*256 + wid*64)*16);
    }
    __syncthreads();
    #pragma unroll
    for(int k2=0;k2<8;++k2){
      const int k16 = kc*8+k2;
      s8v a0 = *(const s8v*)(Xb + (size_t)(r0c>>5)*8192 + (size_t)(k16*2+h)*256 + (r0c&31)*8);
      s8v a1 = *(const s8v*)(Xb + (size_t)(r1c>>5)*8192 + (size_t)(k16*2+h)*256 + (r1c&31)*8);
      #pragma unroll
      for(int n=0;n<4;++n){
        s8v bw = *(const s8v*)(smem + ((k2*8 + wc*4 + n)*64 + lane)*16);
        mfma32(a0, bw, acc[0][n]);
        mfma32(a1, bw, acc[1][n]);
      }
    }
    __syncthreads();
  }

  int lo = 0;
  while(lo < 64){
    int g = __shfl(b_l, lo);
    unsigned long long mb = __ballot(b_l == g);
    int hi = lo + __popcll(mb);
    if(g < GSEG){
      #pragma unroll
      for(int n=0;n<4;++n){
        float sum = 0.f;
        #pragma unroll
        for(int m=0;m<2;++m){
          if(hi <= m*32 || lo >= m*32+32) continue;
          #pragma unroll
          for(int r=0;r<16;++r){
            int lr = m*32 + (r&3) + 8*(r>>2) + 4*h;
            sum += (lr >= lo && lr < hi) ? acc[m][n][r] : 0.f;
          }
        }
        sum += __shfl_xor(sum, 32);
        if(lane < 32) atomicAdd(&gsum[(size_t)g*256 + wc*128 + n*32 + lane], sum);
      }
    }
    lo = hi;
  }
}

// ---------------------------------------------------------------------------
// Weight pack (round-1 VERBATIM): fp32 [K][Dout] -> bf16 fragment-linear
// ---------------------------------------------------------------------------
__global__ void pack_weights(const float* phi_w1, const float* phi_w2,
                             const float* psi_w1, const float* psi_w2,
                             const float* head_w, unsigned short* pw)
{
  int o = (int)blockIdx.x*256 + (int)threadIdx.x;
  if(o >= 167936) return;
  const float* src; unsigned short* dst; int Dout, oo;
  if(o < 32768){        int l=o>>13;            oo=o&8191;  src=phi_w1+(size_t)l*65536;  dst=pw+(size_t)l*65536;           Dout=256; }
  else if(o < 65536){   int t=o-32768,l=t>>13;  oo=t&8191;  src=phi_w2+(size_t)l*65536;  dst=pw+262144+(size_t)l*65536;    Dout=256; }
  else if(o < 131072){  int t=o-65536,l=t>>14;  oo=t&16383; src=psi_w1+(size_t)l*131072; dst=pw+524288+(size_t)l*131072;   Dout=256; }
  else if(o < 163840){  int t=o-131072,l=t>>13; oo=t&8191;  src=psi_w2+(size_t)l*65536;  dst=pw+1048576+(size_t)l*65536;   Dout=256; }
  else{                 oo=o-163840;            src=head_w; dst=pw+1310720;                                                Dout=128; }
  const int NM = Dout/32;
  int lane = oo & 63;
  int m   = (oo>>6) % NM;
  int k16 = (oo>>6) / NM;
  int kb  = k16*16 + (lane>>5)*8;
  int col = m*32 + (lane&31);
  #pragma unroll
  for(int jj=0;jj<8;++jj) dst[(size_t)oo*8 + jj] = f2bs(src[(size_t)(kb+jj)*Dout + col]);
}

// ---------------------------------------------------------------------------
extern "C" void kernel_launch(void* const* d_in, const int* in_sizes, int n_in,
                              void* d_out, int out_size, void* d_ws, size_t ws_size,
                              hipStream_t stream)
{
  (void)in_sizes; (void)n_in; (void)out_size;
  const float* x0       = (const float*)d_in[0];
  const int*   batch    = (const int*)  d_in[1];
  const float* phi_w1   = (const float*)d_in[2];
  const float* phi_b1   = (const float*)d_in[3];
  const float* phi_ln_g = (const float*)d_in[4];
  const float* phi_ln_b = (const float*)d_in[5];
  const float* phi_w2   = (const float*)d_in[6];
  const float* phi_b2   = (const float*)d_in[7];
  const float* psi_w1   = (const float*)d_in[8];
  const float* psi_b1   = (const float*)d_in[9];
  const float* psi_ln_g = (const float*)d_in[10];
  const float* psi_ln_b = (const float*)d_in[11];
  const float* psi_w2   = (const float*)d_in[12];
  const float* psi_b2   = (const float*)d_in[13];
  const float* out_ln_g = (const float*)d_in[14];
  const float* out_ln_b = (const float*)d_in[15];
  const float* head_w   = (const float*)d_in[16];
  const float* head_b   = (const float*)d_in[17];

  char* ws = (char*)d_ws;
  unsigned short* pw = (unsigned short*)ws;               // packed bf16 weights (2.7MB)
  float* gsum        = (float*)(ws + 4194304);            // 524,288 B
  unsigned short* hb = (unsigned short*)(ws + 8388608);   // 102,400,000 B h1/h2 (FL)
  const bool dual = (ws_size >= 315588608ull);
  unsigned short* xb = dual ? (unsigned short*)(ws + 110788608)
                            : (unsigned short*)d_out;     // bf16 state (FL)
  unsigned short* xh = dual ? (unsigned short*)(ws + 213188608) : nullptr; // fp16 state (FL)

  const int grid = (NN + 127)/128;   // 1563

  pack_weights<<<656,256,0,stream>>>(phi_w1, phi_w2, psi_w1, psi_w2, head_w, pw);

  for(int l=0;l<4;++l){
    const unsigned short* pw_phi1 = pw + (size_t)l*65536;
    const unsigned short* pw_phi2 = pw + 262144 + (size_t)l*65536;
    const unsigned short* pw_psi1 = pw + 524288 + (size_t)l*131072;
    const unsigned short* pw_psi2 = pw + 1048576 + (size_t)l*65536;
    const float* b1 = phi_b1 + l*256, *g1 = phi_ln_g + l*256, *n1 = phi_ln_b + l*256;
    const float* b2 = phi_b2 + l*256;
    const float* p1 = psi_b1 + l*256, *pg = psi_ln_g + l*256, *pn = psi_ln_b + l*256;
    const float* p2 = psi_b2 + l*256;
    const float* og = out_ln_g + l*256, *on = out_ln_b + l*256;

    // K1: h1 = LN(relu(x @ phi_w1 + b1))
    if(l==0)
      gemm_ln<256,256,1,0,0,0><<<grid,256,0,stream>>>(nullptr, x0, nullptr, nullptr,
          pw_phi1, b1, g1, n1, nullptr, nullptr, nullptr, hb, nullptr, nullptr);
    else
      gemm_ln<256,256,0,0,0,0><<<grid,256,0,stream>>>(xb, nullptr, nullptr, nullptr,
          pw_phi1, b1, g1, n1, nullptr, nullptr, nullptr, hb, nullptr, nullptr);

    // K2: gsum = segment_sum(h1 @ phi_w2 + b2)
    hipMemsetAsync(gsum, 0, 524288, stream);
    gemm_segsum<<<grid,256,0,stream>>>(hb, pw_phi2, b2, batch, gsum);

    // K3: h2 = LN(relu([x | gsum[batch]] @ psi_w1 + b1'))
    if(l==0)
      gemm_ln<256,512,3,0,0,0><<<grid,256,0,stream>>>(nullptr, x0, gsum, batch,
          pw_psi1, p1, pg, pn, nullptr, nullptr, nullptr, hb, nullptr, nullptr);
    else
      gemm_ln<256,512,2,0,0,0><<<grid,256,0,stream>>>(xb, nullptr, gsum, batch,
          pw_psi1, p1, pg, pn, nullptr, nullptr, nullptr, hb, nullptr, nullptr);

    // K4: x = out_LN(x + h2 @ psi_w2 + b2')
    if(l==0){
      if(dual)
        gemm_ln<256,256,0,1,1,1><<<grid,256,0,stream>>>(hb, nullptr, nullptr, nullptr,
            pw_psi2, p2, og, on, x0, nullptr, nullptr, xb, xh, nullptr);
      else
        gemm_ln<256,256,0,1,1,0><<<grid,256,0,stream>>>(hb, nullptr, nullptr, nullptr,
            pw_psi2, p2, og, on, x0, nullptr, nullptr, xb, nullptr, nullptr);
    } else if(l<3){
      if(dual)
        gemm_ln<256,256,0,1,2,1><<<grid,256,0,stream>>>(hb, nullptr, nullptr, nullptr,
            pw_psi2, p2, og, on, nullptr, xh, nullptr, xb, xh, nullptr);
      else
        gemm_ln<256,256,0,1,3,0><<<grid,256,0,stream>>>(hb, nullptr, nullptr, nullptr,
            pw_psi2, p2, og, on, nullptr, nullptr, xb, xb, nullptr, nullptr);
    } else {
      if(dual)
        gemm_ln<256,256,0,1,2,0><<<grid,256,0,stream>>>(hb, nullptr, nullptr, nullptr,
            pw_psi2, p2, og, on, nullptr, xh, nullptr, xb, nullptr, nullptr);
      else
        gemm_ln<256,256,0,1,3,0><<<grid,256,0,stream>>>(hb, nullptr, nullptr, nullptr,
            pw_psi2, p2, og, on, nullptr, nullptr, xb, xb, nullptr, nullptr);
    }
  }

  // head: out = x @ head_w + head_b (reads FL xb)
  gemm_ln<128,256,0,2,0,0><<<grid,256,0,stream>>>(xb, nullptr, nullptr, nullptr,
      pw + 1310720, head_b, nullptr, nullptr, nullptr, nullptr, nullptr,
      nullptr, nullptr, (float*)d_out);
}

// Round 16
// 1409.282 us; speedup vs baseline: 1.1224x; 1.0738x over previous
//
#include <hip/hip_runtime.h>
#include <stdint.h>

#define DEV __device__ __forceinline__

constexpr int NN = 200000;
constexpr int GSEG = 512;
constexpr int PTILES = (NN + 255) / 256;   // 782 persistent 256-row tiles
constexpr int GRID_P = 256;                // 1 block/CU (128KB LDS resident weights)

typedef __attribute__((ext_vector_type(8)))  short   s8v;   // 8 bf16/fp16 bits
typedef __attribute__((ext_vector_type(4)))  float   f4v;
typedef __attribute__((ext_vector_type(16))) float   f16v;
typedef __attribute__((ext_vector_type(4)))  unsigned short u4v;
typedef __attribute__((ext_vector_type(4)))  _Float16 h4v;

DEV void mfma32(const s8v& a, const s8v& b, f16v& c){
  asm volatile("v_mfma_f32_32x32x16_bf16 %0, %1, %2, %0" : "+v"(c) : "v"(a), "v"(b));
}

DEV unsigned short f2bs(float f){
  union { float f; uint32_t u; } v; v.f = f;
  uint32_t u = v.u;
  u = u + 0x7fffu + ((u >> 16) & 1u);          // RNE
  return (unsigned short)(u >> 16);
}
DEV float b2f(unsigned short s){
  union { uint32_t u; float f; } v; v.u = ((uint32_t)s) << 16;
  return v.f;
}
DEV unsigned short f2h(float f){
  union{ _Float16 h; unsigned short u; } v; v.h = (_Float16)f; return v.u;
}
DEV s8v cvt8(f4v a, f4v b){
  s8v r;
  r[0]=(short)f2bs(a[0]); r[1]=(short)f2bs(a[1]); r[2]=(short)f2bs(a[2]); r[3]=(short)f2bs(a[3]);
  r[4]=(short)f2bs(b[0]); r[5]=(short)f2bs(b[1]); r[6]=(short)f2bs(b[2]); r[7]=(short)f2bs(b[3]);
  return r;
}

DEV void gload_lds16(const void* g, void* l){
  __builtin_amdgcn_global_load_lds(
      (const __attribute__((address_space(1))) void*)g,
      (__attribute__((address_space(3))) void*)l, 16, 0, 0);
}

DEV u4v shfl_xor32_u4(u4v v){
  union { u4v q; long long l; } a, b;
  a.q = v;
  b.l = __shfl_xor(a.l, 32);
  return b.q;
}

// ---------------------------------------------------------------------------
// FL (fragment-linear) state layout (R12-verified):
//   16B unit (node n, col-octet o) at short-offset (n>>5)*8192 + o*256 + (n&31)*8.
// ---------------------------------------------------------------------------

// B-fragment loader (R12 verbatim).
// BSRC: 0 = bf16 X(FL); 1 = f32 X; 2/3 = concat forms (head template only).
template<int BSRC>
DEV s8v load_bfrag(const unsigned short* Xb, const float* Xf, const float* gsum,
                   int row, int g, int k16, int h){
  if constexpr(BSRC==0){
    return *(const s8v*)(Xb + (size_t)(row>>5)*8192 + (size_t)(k16*2+h)*256 + (row&31)*8);
  } else if constexpr(BSRC==1){
    const float* p = Xf + (size_t)row*256 + k16*16 + h*8;
    return cvt8(*(const f4v*)p, *(const f4v*)(p+4));
  } else if constexpr(BSRC==2){
    if(k16 < 16)
      return *(const s8v*)(Xb + (size_t)(row>>5)*8192 + (size_t)(k16*2+h)*256 + (row&31)*8);
    const float* p = gsum + (size_t)g*256 + (k16-16)*16 + h*8;
    return cvt8(*(const f4v*)p, *(const f4v*)(p+4));
  } else {
    if(k16 < 16){
      const float* p = Xf + (size_t)row*256 + k16*16 + h*8;
      return cvt8(*(const f4v*)p, *(const f4v*)(p+4));
    }
    const float* p = gsum + (size_t)g*256 + (k16-16)*16 + h*8;
    return cvt8(*(const f4v*)p, *(const f4v*)(p+4));
  }
}

// ---------------------------------------------------------------------------
// gemm_pers — persistent-block K=256 / DOUT=256 GEMM+LN.
// 512 threads (8 waves: wr=wid>>1 in 0..3 row-group, wc=wid&1 col-half),
// ALL weights (128KB) staged into LDS once; grid-stride loop over 256-row
// tiles with a barrier-free K-loop (R8-proven class) and one barrier/tile
// for the LN stats exchange (parity double-buffered).
// Per-wave program (acc[2][4], k2 body, FL loads, epilogue) = R12/R14 verbatim.
// MODE: 0 = LN(relu(.)) -> bf16 FL out
//       1 = (.)+residual, out_LN -> bf16 FL out (+ fp16 FL out if WRH)
// RES:  1 = f32 row-major residual (L0), 2 = fp16 FL, 3 = bf16 FL
// INITG: 1 = acc init from gy[batch[row]] (K3 gsum-half precomputed), else bias.
// ---------------------------------------------------------------------------
template<int BSRC,int MODE,int RES,int WRH,int INITG>
__global__ __launch_bounds__(512,1) void gemm_pers(
    const unsigned short* Xb, const float* Xf, const float* gyIn, const int* batch,
    const unsigned short* PW, const float* bias, const float* lng, const float* lnb,
    const float* xresf, const unsigned short* xresh, const unsigned short* xresb,
    unsigned short* outb, unsigned short* outh, int ntiles)
{
  __shared__ __align__(16) char sW[131072];           // 16 k16-slices x 8KB
  __shared__ __align__(16) float2 sStat[2][8][32][2]; // [parity][slot][l32][wc]

  const int tid = threadIdx.x, lane = tid & 63, wid = tid >> 6;
  const int wr = wid >> 1, wc = wid & 1;
  const int l32 = lane & 31, h = lane >> 5;

  // one-time weight stage (proven pattern: per-lane global src, uniform LDS base)
  #pragma unroll
  for(int it=0; it<16; ++it)
    gload_lds16(PW + (size_t)(it*512 + wid*64 + lane)*8,
                sW + (it*512 + wid*64)*16);
  __syncthreads();

  int tp = 0;
  for(int t = (int)blockIdx.x; t < ntiles; t += (int)gridDim.x, tp ^= 1){
    const int rb   = t * 256;
    const int row0 = rb + wr*64 + l32;
    const int row1 = row0 + 32;
    const int r0c = row0 < NN ? row0 : NN-1;
    const int r1c = row1 < NN ? row1 : NN-1;

    int g0=0, g1=0;
    if constexpr(INITG){ g0 = batch[r0c]; g1 = batch[r1c]; }

    f16v acc[2][4];
    #pragma unroll
    for(int ni=0; ni<4; ++ni){
      #pragma unroll
      for(int rq=0; rq<4; ++rq){
        const int c4 = wc*128 + ni*32 + 8*rq + 4*h;
        if constexpr(INITG){
          f4v a0 = *(const f4v*)(gyIn + (size_t)g0*256 + c4);
          f4v a1 = *(const f4v*)(gyIn + (size_t)g1*256 + c4);
          #pragma unroll
          for(int j=0;j<4;++j){ acc[0][ni][rq*4+j]=a0[j]; acc[1][ni][rq*4+j]=a1[j]; }
        } else {
          f4v bv = *(const f4v*)(bias + c4);
          #pragma unroll
          for(int j=0;j<4;++j){ acc[0][ni][rq*4+j]=bv[j]; acc[1][ni][rq*4+j]=bv[j]; }
        }
      }
    }

    #pragma unroll 4
    for(int k16=0; k16<16; ++k16){
      s8v b0 = load_bfrag<BSRC>(Xb, Xf, nullptr, r0c, 0, k16, h);
      s8v b1 = load_bfrag<BSRC>(Xb, Xf, nullptr, r1c, 0, k16, h);
      #pragma unroll
      for(int ni=0; ni<4; ++ni){
        s8v a = *(const s8v*)(sW + ((k16*8 + wc*4 + ni)*64 + lane)*16);
        mfma32(a, b0, acc[0][ni]);
        mfma32(a, b1, acc[1][ni]);
      }
    }

    // residual add (MODE1) or relu (MODE0) — R12 body verbatim
    #pragma unroll
    for(int nj=0;nj<2;++nj){
      if constexpr(MODE==1){
        const int rr = nj ? r1c : r0c;
        #pragma unroll
        for(int ni=0;ni<4;++ni){
          #pragma unroll
          for(int rq=0;rq<4;++rq){
            const int c4 = wc*128 + ni*32 + 8*rq + 4*h;
            f4v rv;
            if constexpr(RES==1){
              rv = *(const f4v*)(xresf + (size_t)rr*256 + c4);
            } else if constexpr(RES==2){
              const int o = wc*16 + ni*4 + rq;
              h4v hv = *(const h4v*)(xresh + (size_t)(rr>>5)*8192 + (size_t)o*256 + (rr&31)*8 + 4*h);
              #pragma unroll
              for(int j=0;j<4;++j) rv[j] = (float)hv[j];
            } else {
              const int o = wc*16 + ni*4 + rq;
              u4v u = *(const u4v*)(xresb + (size_t)(rr>>5)*8192 + (size_t)o*256 + (rr&31)*8 + 4*h);
              #pragma unroll
              for(int j=0;j<4;++j) rv[j] = b2f(u[j]);
            }
            #pragma unroll
            for(int j=0;j<4;++j) acc[nj][ni][rq*4+j] += rv[j];
          }
        }
      } else {
        #pragma unroll
        for(int ni=0;ni<4;++ni)
          #pragma unroll
          for(int r=0;r<16;++r) acc[nj][ni][r] = fmaxf(acc[nj][ni][r], 0.f);
      }
    }
    // row stats: slot = wr*2+nj, parity tp (double-buffered; skew<=1 tile)
    float s[2]={0.f,0.f}, q[2]={0.f,0.f};
    #pragma unroll
    for(int nj=0;nj<2;++nj)
      #pragma unroll
      for(int ni=0;ni<4;++ni)
        #pragma unroll
        for(int r=0;r<16;++r){ float v = acc[nj][ni][r]; s[nj]+=v; q[nj]=fmaf(v,v,q[nj]); }
    #pragma unroll
    for(int nj=0;nj<2;++nj){ s[nj] += __shfl_xor(s[nj],32); q[nj] += __shfl_xor(q[nj],32); }
    if(lane < 32){
      sStat[tp][wr*2+0][lane][wc] = make_float2(s[0], q[0]);
      sStat[tp][wr*2+1][lane][wc] = make_float2(s[1], q[1]);
    }
    __syncthreads();
    float mu[2], rs[2];
    #pragma unroll
    for(int nj=0;nj<2;++nj){
      f4v v = *(const f4v*)(&sStat[tp][wr*2+nj][l32][0]);
      float S = v[0]+v[2], Q = v[1]+v[3];
      mu[nj] = S*(1.f/256.f);
      float var = Q*(1.f/256.f) - mu[nj]*mu[nj];
      rs[nj] = rsqrtf(var + 1e-5f);
    }
    // ---- FL state store (R12-verified body) ----
    #pragma unroll
    for(int nj=0;nj<2;++nj){
      const int rowS = nj ? row1 : row0;
      #pragma unroll
      for(int ot=0;ot<8;++ot){
        const int niE = (16*ot)>>5,     rqE = (2*ot)&3;
        const int niO = (16*ot+8)>>5,   rqO = (2*ot+1)&3;
        f4v fe, fo;
        {
          const int c4 = wc*128 + niE*32 + 8*rqE + 4*h;
          f4v gv = *(const f4v*)(lng + c4);
          f4v bv = *(const f4v*)(lnb + c4);
          #pragma unroll
          for(int j=0;j<4;++j)
            fe[j] = fmaf((acc[nj][niE][rqE*4+j]-mu[nj])*rs[nj], gv[j], bv[j]);
        }
        {
          const int c4 = wc*128 + niO*32 + 8*rqO + 4*h;
          f4v gv = *(const f4v*)(lng + c4);
          f4v bv = *(const f4v*)(lnb + c4);
          #pragma unroll
          for(int j=0;j<4;++j)
            fo[j] = fmaf((acc[nj][niO][rqO*4+j]-mu[nj])*rs[nj], gv[j], bv[j]);
        }
        const int o = wc*16 + 2*ot + h;
        {
          u4v qe, qo;
          #pragma unroll
          for(int j=0;j<4;++j){ qe[j] = f2bs(fe[j]); qo[j] = f2bs(fo[j]); }
          u4v snd = h ? qe : qo;
          u4v rcv = shfl_xor32_u4(snd);
          u4v lo4 = h ? rcv : qe;
          u4v hi4 = h ? qo  : rcv;
          if(rowS < NN){
            s8v ov;
            #pragma unroll
            for(int j=0;j<4;++j){ ov[j] = (short)lo4[j]; ov[4+j] = (short)hi4[j]; }
            *(s8v*)(outb + (size_t)(rowS>>5)*8192 + (size_t)o*256 + (rowS&31)*8) = ov;
          }
        }
        if constexpr(WRH){
          u4v qe, qo;
          #pragma unroll
          for(int j=0;j<4;++j){ qe[j] = f2h(fe[j]); qo[j] = f2h(fo[j]); }
          u4v snd = h ? qe : qo;
          u4v rcv = shfl_xor32_u4(snd);
          u4v lo4 = h ? rcv : qe;
          u4v hi4 = h ? qo  : rcv;
          if(rowS < NN){
            s8v ov;
            #pragma unroll
            for(int j=0;j<4;++j){ ov[j] = (short)lo4[j]; ov[4+j] = (short)hi4[j]; }
            *(s8v*)(outh + (size_t)(rowS>>5)*8192 + (size_t)o*256 + (rowS&31)*8) = ov;
          }
        }
      }
    }
  }
}

// ---------------------------------------------------------------------------
// segsum_pers — persistent-block K2: phi = h1 @ W2 + b2, segment-sum to gsum.
// Weights resident (128KB); ZERO barriers in the tile loop (no LDS reuse,
// no stats). Ballot/atomic epilogue = R12 verbatim per 64-row wave group.
// ---------------------------------------------------------------------------
__global__ __launch_bounds__(512,1) void segsum_pers(
    const unsigned short* Xb, const unsigned short* PW, const float* bias,
    const int* batch, float* gsum, int ntiles)
{
  __shared__ __align__(16) char sW[131072];
  const int tid = threadIdx.x, lane = tid & 63, wid = tid >> 6;
  const int wr = wid >> 1, wc = wid & 1;
  const int l32 = lane & 31, h = lane >> 5;

  #pragma unroll
  for(int it=0; it<16; ++it)
    gload_lds16(PW + (size_t)(it*512 + wid*64 + lane)*8,
                sW + (it*512 + wid*64)*16);
  __syncthreads();

  for(int t = (int)blockIdx.x; t < ntiles; t += (int)gridDim.x){
    const int rb = t * 256;
    const int ra0 = rb + wr*64 + l32;
    const int ra1 = ra0 + 32;
    const int r0c = ra0 < NN ? ra0 : NN-1;
    const int r1c = ra1 < NN ? ra1 : NN-1;
    const int browi = rb + wr*64 + lane;
    const int b_l = (browi < NN) ? batch[browi] : 0x7fffffff;

    f16v acc[2][4];
    #pragma unroll
    for(int n=0;n<4;++n){
      float bv = bias[wc*128 + n*32 + l32];
      #pragma unroll
      for(int m=0;m<2;++m)
        #pragma unroll
        for(int r=0;r<16;++r) acc[m][n][r] = bv;
    }

    #pragma unroll 4
    for(int k16=0; k16<16; ++k16){
      s8v a0 = *(const s8v*)(Xb + (size_t)(r0c>>5)*8192 + (size_t)(k16*2+h)*256 + (r0c&31)*8);
      s8v a1 = *(const s8v*)(Xb + (size_t)(r1c>>5)*8192 + (size_t)(k16*2+h)*256 + (r1c&31)*8);
      #pragma unroll
      for(int n=0;n<4;++n){
        s8v bw = *(const s8v*)(sW + ((k16*8 + wc*4 + n)*64 + lane)*16);
        mfma32(a0, bw, acc[0][n]);
        mfma32(a1, bw, acc[1][n]);
      }
    }

    int lo = 0;
    while(lo < 64){
      int g = __shfl(b_l, lo);
      unsigned long long mb = __ballot(b_l == g);
      int hi = lo + __popcll(mb);
      if(g < GSEG){
        #pragma unroll
        for(int n=0;n<4;++n){
          float sum = 0.f;
          #pragma unroll
          for(int m=0;m<2;++m){
            if(hi <= m*32 || lo >= m*32+32) continue;
            #pragma unroll
            for(int r=0;r<16;++r){
              int lr = m*32 + (r&3) + 8*(r>>2) + 4*h;
              sum += (lr >= lo && lr < hi) ? acc[m][n][r] : 0.f;
            }
          }
          sum += __shfl_xor(sum, 32);
          if(lane < 32) atomicAdd(&gsum[(size_t)g*256 + wc*128 + n*32 + lane], sum);
        }
      }
      lo = hi;
    }
  }
}

// ---------------------------------------------------------------------------
// gy_k: gy[512][256] = bf16MFMA(bf16(gsum) @ Wpsi1_hi) + psi_b1.
// Tiny (512 rows); R12 chunked K-loop shape; direct f32 stores.
// ---------------------------------------------------------------------------
__global__ __launch_bounds__(256,2) void gy_k(
    const float* gsum, const unsigned short* PWhi, const float* bias, float* gy)
{
  __shared__ __align__(16) char smem[32768];
  const int tid = threadIdx.x, lane = tid & 63, wid = tid >> 6;
  const int wr = wid >> 1, wc = wid & 1;
  const int l32 = lane & 31, h = lane >> 5;
  const int rb = (int)blockIdx.x * 128;         // 4 blocks x 128 = 512 rows exact
  const int row0 = rb + wr*64 + l32;
  const int row1 = row0 + 32;

  f16v acc[2][4];
  #pragma unroll
  for(int ni=0;ni<4;++ni){
    #pragma unroll
    for(int rq=0;rq<4;++rq){
      f4v bv = *(const f4v*)(bias + wc*128 + ni*32 + 8*rq + 4*h);
      #pragma unroll
      for(int j=0;j<4;++j){ acc[0][ni][rq*4+j]=bv[j]; acc[1][ni][rq*4+j]=bv[j]; }
    }
  }

  for(int kc=0; kc<4; ++kc){
    const unsigned short* src = PWhi + (size_t)kc*16384;
    #pragma unroll
    for(int it=0; it<8; ++it){
      int idx = it*256 + tid;
      gload_lds16(src + (size_t)idx*8, smem + (it*256 + wid*64)*16);
    }
    __syncthreads();
    #pragma unroll
    for(int k2=0;k2<4;++k2){
      const int k16 = kc*4 + k2;
      const float* p0 = gsum + (size_t)row0*256 + k16*16 + h*8;
      const float* p1 = gsum + (size_t)row1*256 + k16*16 + h*8;
      s8v b0 = cvt8(*(const f4v*)p0, *(const f4v*)(p0+4));
      s8v b1 = cvt8(*(const f4v*)p1, *(const f4v*)(p1+4));
      #pragma unroll
      for(int ni=0;ni<4;++ni){
        s8v a = *(const s8v*)(smem + ((k2*8 + wc*4 + ni)*64 + lane)*16);
        mfma32(a, b0, acc[0][ni]);
        mfma32(a, b1, acc[1][ni]);
      }
    }
    __syncthreads();
  }

  #pragma unroll
  for(int nj=0;nj<2;++nj){
    const int rowS = nj ? row1 : row0;
    #pragma unroll
    for(int ni=0;ni<4;++ni){
      #pragma unroll
      for(int rq=0;rq<4;++rq){
        const int c4 = wc*128 + ni*32 + 8*rq + 4*h;
        f4v o;
        #pragma unroll
        for(int j=0;j<4;++j) o[j] = acc[nj][ni][rq*4+j];
        *(f4v*)(gy + (size_t)rowS*256 + c4) = o;
      }
    }
  }
}

// ---------------------------------------------------------------------------
// Head kernel — R12's gemm_ln MODE2 (DOUT=128, K=256, FL xb input), VERBATIM.
// ---------------------------------------------------------------------------
template<int DOUT,int KDIM,int BSRC,int MODE,int RES,int WRH>
__global__ __launch_bounds__(256,2) void gemm_ln(
    const unsigned short* Xb, const float* Xf, const float* gsumIn, const int* batch,
    const unsigned short* PW, const float* bias, const float* lng, const float* lnb,
    const float* xresf, const unsigned short* xresh, const unsigned short* xresb,
    unsigned short* outb, unsigned short* outh, float* outf)
{
  constexpr int NM  = DOUT/32;
  constexpr int NI  = DOUT/64;
  constexpr int CHB = NM*4096;
  constexpr int ITER= CHB/4096;
  __shared__ __align__(16) char smem[CHB + 2048];
  __shared__ __align__(16) char sT[(MODE==2) ? 32768 : 16];

  const int tid  = threadIdx.x;
  const int lane = tid & 63;
  const int wid  = tid >> 6;
  const int wr = wid >> 1, wc = wid & 1;
  const int l32 = lane & 31, h = lane >> 5;
  const int rb   = (int)blockIdx.x * 128;
  const int row0 = rb + wr*64 + l32;
  const int row1 = row0 + 32;
  const int r0c = row0 < NN ? row0 : NN-1;
  const int r1c = row1 < NN ? row1 : NN-1;

  f16v acc[2][NI];
  #pragma unroll
  for(int ni=0; ni<NI; ++ni){
    #pragma unroll
    for(int rq=0; rq<4; ++rq){
      f4v bv = *(const f4v*)(bias + wc*(DOUT/2) + ni*32 + 8*rq + 4*h);
      #pragma unroll
      for(int j=0;j<4;++j){ acc[0][ni][rq*4+j]=bv[j]; acc[1][ni][rq*4+j]=bv[j]; }
    }
  }

  int g0=0, g1=0;
  if constexpr(BSRC>=2){ g0 = batch[r0c]; g1 = batch[r1c]; }

  for(int kc=0; kc<KDIM/64; ++kc){
    const unsigned short* src = PW + (size_t)kc*(CHB/2);
    #pragma unroll
    for(int it=0; it<ITER; ++it){
      int idx = it*256 + tid;
      gload_lds16(src + (size_t)idx*8, smem + (it*256 + wid*64)*16);
    }
    __syncthreads();
    #pragma unroll
    for(int k2=0;k2<4;++k2){
      const int k16 = kc*4 + k2;
      s8v b0 = load_bfrag<BSRC>(Xb, Xf, gsumIn, r0c, g0, k16, h);
      s8v b1 = load_bfrag<BSRC>(Xb, Xf, gsumIn, r1c, g1, k16, h);
      #pragma unroll
      for(int ni=0; ni<NI; ++ni){
        s8v a = *(const s8v*)(smem + ((k2*NM + wc*NI + ni)*64 + lane)*16);
        mfma32(a, b0, acc[0][ni]);
        mfma32(a, b1, acc[1][ni]);
      }
    }
    __syncthreads();
  }

  // MODE2 only in this build: f32 row-major chunked transpose store via sT
  for(int chunk=0; chunk<2; ++chunk){
    if(chunk) __syncthreads();
    if(wr == chunk){
      #pragma unroll
      for(int nj=0;nj<2;++nj){
        #pragma unroll
        for(int ni=0;ni<NI;++ni){
          #pragma unroll
          for(int rq=0;rq<4;++rq){
            const int c4 = wc*(DOUT/2) + ni*32 + 8*rq + 4*h;
            f4v o;
            #pragma unroll
            for(int j=0;j<4;++j) o[j] = acc[nj][ni][rq*4+j];
            *(f4v*)(sT + (nj*32+l32)*512 + ((c4*4) ^ (l32<<4))) = o;
          }
        }
      }
    }
    __syncthreads();
    #pragma unroll
    for(int i=0;i<8;++i){
      const int r = i*8 + (tid>>5);
      const int c = tid & 31;
      const int grow = rb + chunk*64 + r;
      if(grow < NN)
        *(f4v*)(outf + (size_t)grow*DOUT + c*4) =
            *(const f4v*)(sT + r*512 + ((c*16) ^ ((r&31)<<4)));
    }
  }
}

// ---------------------------------------------------------------------------
// Weight pack (round-1 VERBATIM): fp32 [K][Dout] -> bf16 fragment-linear
// ---------------------------------------------------------------------------
__global__ void pack_weights(const float* phi_w1, const float* phi_w2,
                             const float* psi_w1, const float* psi_w2,
                             const float* head_w, unsigned short* pw)
{
  int o = (int)blockIdx.x*256 + (int)threadIdx.x;
  if(o >= 167936) return;
  const float* src; unsigned short* dst; int Dout, oo;
  if(o < 32768){        int l=o>>13;            oo=o&8191;  src=phi_w1+(size_t)l*65536;  dst=pw+(size_t)l*65536;           Dout=256; }
  else if(o < 65536){   int t=o-32768,l=t>>13;  oo=t&8191;  src=phi_w2+(size_t)l*65536;  dst=pw+262144+(size_t)l*65536;    Dout=256; }
  else if(o < 131072){  int t=o-65536,l=t>>14;  oo=t&16383; src=psi_w1+(size_t)l*131072; dst=pw+524288+(size_t)l*131072;   Dout=256; }
  else if(o < 163840){  int t=o-131072,l=t>>13; oo=t&8191;  src=psi_w2+(size_t)l*65536;  dst=pw+1048576+(size_t)l*65536;   Dout=256; }
  else{                 oo=o-163840;            src=head_w; dst=pw+1310720;                                                Dout=128; }
  const int NM = Dout/32;
  int lane = oo & 63;
  int m   = (oo>>6) % NM;
  int k16 = (oo>>6) / NM;
  int kb  = k16*16 + (lane>>5)*8;
  int col = m*32 + (lane&31);
  #pragma unroll
  for(int jj=0;jj<8;++jj) dst[(size_t)oo*8 + jj] = f2bs(src[(size_t)(kb+jj)*Dout + col]);
}

// ---------------------------------------------------------------------------
extern "C" void kernel_launch(void* const* d_in, const int* in_sizes, int n_in,
                              void* d_out, int out_size, void* d_ws, size_t ws_size,
                              hipStream_t stream)
{
  (void)in_sizes; (void)n_in; (void)out_size;
  const float* x0       = (const float*)d_in[0];
  const int*   batch    = (const int*)  d_in[1];
  const float* phi_w1   = (const float*)d_in[2];
  const float* phi_b1   = (const float*)d_in[3];
  const float* phi_ln_g = (const float*)d_in[4];
  const float* phi_ln_b = (const float*)d_in[5];
  const float* phi_w2   = (const float*)d_in[6];
  const float* phi_b2   = (const float*)d_in[7];
  const float* psi_w1   = (const float*)d_in[8];
  const float* psi_b1   = (const float*)d_in[9];
  const float* psi_ln_g = (const float*)d_in[10];
  const float* psi_ln_b = (const float*)d_in[11];
  const float* psi_w2   = (const float*)d_in[12];
  const float* psi_b2   = (const float*)d_in[13];
  const float* out_ln_g = (const float*)d_in[14];
  const float* out_ln_b = (const float*)d_in[15];
  const float* head_w   = (const float*)d_in[16];
  const float* head_b   = (const float*)d_in[17];

  char* ws = (char*)d_ws;
  unsigned short* pw = (unsigned short*)ws;               // packed bf16 weights (2.7MB)
  float* gsum        = (float*)(ws + 4194304);            // 512KB
  float* gy          = (float*)(ws + 4718592);            // 512KB (gsum-half of psi1)
  unsigned short* hb = (unsigned short*)(ws + 8388608);   // 100MB h1/h2 (FL)
  const bool dual = (ws_size >= 315588608ull);
  unsigned short* xb = dual ? (unsigned short*)(ws + 110788608)
                            : (unsigned short*)d_out;     // bf16 state (FL)
  unsigned short* xh = dual ? (unsigned short*)(ws + 213188608) : nullptr; // fp16 state (FL)

  pack_weights<<<656,256,0,stream>>>(phi_w1, phi_w2, psi_w1, psi_w2, head_w, pw);

  for(int l=0;l<4;++l){
    const unsigned short* pw_phi1 = pw + (size_t)l*65536;
    const unsigned short* pw_phi2 = pw + 262144 + (size_t)l*65536;
    const unsigned short* pw_psi1 = pw + 524288 + (size_t)l*131072;  // slices 0..31
    const unsigned short* pw_psi2 = pw + 1048576 + (size_t)l*65536;
    const float* b1 = phi_b1 + l*256, *g1 = phi_ln_g + l*256, *n1 = phi_ln_b + l*256;
    const float* b2 = phi_b2 + l*256;
    const float* p1 = psi_b1 + l*256, *pg = psi_ln_g + l*256, *pn = psi_ln_b + l*256;
    const float* p2 = psi_b2 + l*256;
    const float* og = out_ln_g + l*256, *on = out_ln_b + l*256;

    // K1: h1 = LN(relu(x @ phi_w1 + b1))
    if(l==0)
      gemm_pers<1,0,0,0,0><<<GRID_P,512,0,stream>>>(nullptr, x0, nullptr, nullptr,
          pw_phi1, b1, g1, n1, nullptr, nullptr, nullptr, hb, nullptr, PTILES);
    else
      gemm_pers<0,0,0,0,0><<<GRID_P,512,0,stream>>>(xb, nullptr, nullptr, nullptr,
          pw_phi1, b1, g1, n1, nullptr, nullptr, nullptr, hb, nullptr, PTILES);

    // K2: gsum = segment_sum(h1 @ phi_w2 + b2)
    hipMemsetAsync(gsum, 0, 524288, stream);
    segsum_pers<<<GRID_P,512,0,stream>>>(hb, pw_phi2, b2, batch, gsum, PTILES);

    // gy = bf16(gsum) @ psi_w1[256:512] + psi_b1   (512x256, tiny)
    gy_k<<<4,256,0,stream>>>(gsum, pw_psi1 + 65536, p1, gy);

    // K3: h2 = LN(relu(x @ psi_w1[0:256] + gy[batch]))
    if(l==0)
      gemm_pers<1,0,0,0,1><<<GRID_P,512,0,stream>>>(nullptr, x0, gy, batch,
          pw_psi1, nullptr, pg, pn, nullptr, nullptr, nullptr, hb, nullptr, PTILES);
    else
      gemm_pers<0,0,0,0,1><<<GRID_P,512,0,stream>>>(xb, nullptr, gy, batch,
          pw_psi1, nullptr, pg, pn, nullptr, nullptr, nullptr, hb, nullptr, PTILES);

    // K4: x = out_LN(x + h2 @ psi_w2 + b2')
    if(l==0){
      if(dual)
        gemm_pers<0,1,1,1,0><<<GRID_P,512,0,stream>>>(hb, nullptr, nullptr, nullptr,
            pw_psi2, p2, og, on, x0, nullptr, nullptr, xb, xh, PTILES);
      else
        gemm_pers<0,1,1,0,0><<<GRID_P,512,0,stream>>>(hb, nullptr, nullptr, nullptr,
            pw_psi2, p2, og, on, x0, nullptr, nullptr, xb, nullptr, PTILES);
    } else if(l<3){
      if(dual)
        gemm_pers<0,1,2,1,0><<<GRID_P,512,0,stream>>>(hb, nullptr, nullptr, nullptr,
            pw_psi2, p2, og, on, nullptr, xh, nullptr, xb, xh, PTILES);
      else
        gemm_pers<0,1,3,0,0><<<GRID_P,512,0,stream>>>(hb, nullptr, nullptr, nullptr,
            pw_psi2, p2, og, on, nullptr, nullptr, xb, xb, nullptr, PTILES);
    } else {
      if(dual)
        gemm_pers<0,1,2,0,0><<<GRID_P,512,0,stream>>>(hb, nullptr, nullptr, nullptr,
            pw_psi2, p2, og, on, nullptr, xh, nullptr, xb, nullptr, PTILES);
      else
        gemm_pers<0,1,3,0,0><<<GRID_P,512,0,stream>>>(hb, nullptr, nullptr, nullptr,
            pw_psi2, p2, og, on, nullptr, nullptr, xb, xb, nullptr, PTILES);
    }
  }

  // head: out = x @ head_w + head_b (reads FL xb)
  gemm_ln<128,256,0,2,0,0><<<(NN+127)/128,256,0,stream>>>(xb, nullptr, nullptr, nullptr,
      pw + 1310720, head_b, nullptr, nullptr, nullptr, nullptr, nullptr,
      nullptr, nullptr, (float*)d_out);
}